// Round 13
// baseline (885.023 us; speedup 1.0000x reference)
//
#include <hip/hip_runtime.h>
#include <stdint.h>

typedef int v4i  __attribute__((ext_vector_type(4)));
typedef int v16i __attribute__((ext_vector_type(16)));

#define CAPACITY  65536
#define BATCH     2048
#define KBITS     1024
#define NSTEP     16      // K-steps of 64 bytes

// ===========================================================================
// MFMA path: dist(q,k) = sumq + sumk - 2*dot(q,k). sumq constant per query
// row -> dropped; rank by packed ((sumk - 2*dot + 2048)<<16) | key_idx, exact
// (0 <= biased dist <= 3072 < 2^16), reproduces first-max argmax.
//
// BARRIER-FREE design: 1 wave per block, 64x64 tile, private 8 KB LDS for B
// (global_load_lds, NBUF=2), A direct from blocked-transposed global. All
// ordering is same-wave vmcnt/lgkmcnt; restage of a buffer happens only
// after lgkmcnt(0) proves our own reads of it completed. 16 independent
// waves/CU at free-running phases -> pipes overlap by construction.
// ===========================================================================

// ---- queries: bits -> i8, blocked-transposed qT[k/16][m][16] ----------------
__global__ void prep_qT_kernel(const int* __restrict__ in,
                               uint32_t* __restrict__ outT) {
    const int row = blockIdx.x, t = threadIdx.x;   // t covers bits 4t..4t+3
    int4 v = reinterpret_cast<const int4*>(in)[(size_t)row * 256 + t];
    uint32_t b = (uint32_t)(v.x & 1)        | ((uint32_t)(v.y & 1) << 8) |
                 ((uint32_t)(v.z & 1) << 16) | ((uint32_t)(v.w & 1) << 24);
    outT[(size_t)(t >> 2) * (BATCH * 4) + (size_t)row * 4 + (t & 3)] = b;
}

// ---- keys: bits -> i8 row-major, plus per-row bit count ---------------------
__global__ void prep_i8_kernel(const int* __restrict__ in,
                               unsigned char* __restrict__ out8,
                               int* __restrict__ sums) {
    const int row = blockIdx.x, t = threadIdx.x;
    int4 v = reinterpret_cast<const int4*>(in)[(size_t)row * 256 + t];
    uint32_t b = (uint32_t)(v.x & 1)        | ((uint32_t)(v.y & 1) << 8) |
                 ((uint32_t)(v.z & 1) << 16) | ((uint32_t)(v.w & 1) << 24);
    reinterpret_cast<uint32_t*>(out8)[(size_t)row * 256 + t] = b;
    int s = (v.x & 1) + (v.y & 1) + (v.z & 1) + (v.w & 1);
    for (int off = 32; off; off >>= 1) s += __shfl_xor(s, off, 64);
    __shared__ int ws4[4];
    if ((t & 63) == 0) ws4[t >> 6] = s;
    __syncthreads();
    if (t == 0) sums[row] = ws4[0] + ws4[1] + ws4[2] + ws4[3];
}

__global__ void init_best_kernel(uint32_t* __restrict__ best) {
    best[blockIdx.x * 256 + threadIdx.x] = 0xFFFFFFFFu;
}

// Involutive 16B-chunk swizzle within a [rows][64B] tile (idx = row*4+chunk):
// self-inverse, spreads consecutive rows across bank groups.
__device__ __forceinline__ int swz(int idx) { return idx ^ ((idx >> 3) & 7); }

// ---- GEMM + fused argmin, barrier-free --------------------------------------
// Per step s: ds_read bf (buf s&1) ; issue af(s) ; lgkmcnt(0) ; restage
// buf[s&1] with k(s+2) ; vmcnt(4) [af(s)+stage(s+1) done, stage(s+2) in
// flight] ; 8 mfma. No s_barrier anywhere.
__launch_bounds__(64, 4)
__global__ void gemm_scan_kernel(const uint4* __restrict__ aT4,
                                 const unsigned char* __restrict__ ki8,
                                 const int* __restrict__ sumk,
                                 uint32_t* __restrict__ best) {
    __shared__ uint4 sB[2][256];   // 2 x (64 rows x 4 chunks) = 8 KB, private

    const int t    = threadIdx.x;            // 64 threads = 1 wave
    const int ln   = t & 31, kh = t >> 5;    // mfma lane row, k-half

    // XCD-pinned, ntile-INNER: xcd = b&7 owns 128 ntiles; consecutive slots
    // share mtile -> A panel L1/L2-hot; B streams (64 MB ki8 is L3-resident).
    const int b     = blockIdx.x;
    const int slot  = b >> 3;                       // [0, 4096)
    const int mtile = slot >> 7;                    // [0, 32)
    const int ntile = (b & 7) * 128 + (slot & 127); // [0, 1024)
    const int m0 = mtile * 64, n0 = ntile * 64;

    // B staging sources, pre-swizzled (swz involution; LDS dest linear).
    const unsigned char* bSrc[4];
#pragma unroll
    for (int i = 0; i < 4; ++i) {
        int idx = swz(i * 64 + t);
        bSrc[i] = ki8 + (size_t)(n0 + (idx >> 2)) * KBITS + (idx & 3) * 16;
    }
    auto STAGE_B = [&](int buf, int kc) {           // 4 x global_load_lds(16B)
#pragma unroll
        for (int i = 0; i < 4; ++i)
            __builtin_amdgcn_global_load_lds(
                (const __attribute__((address_space(1))) void*)(bSrc[i] + kc),
                (__attribute__((address_space(3))) void*)&sB[buf][i * 64],
                16, 0, 0);
    };

    // B fragment LDS offsets (K-invariant)
    int offB[2][2];
#pragma unroll
    for (int km = 0; km < 2; ++km)
#pragma unroll
        for (int ct = 0; ct < 2; ++ct)
            offB[km][ct] = swz((ct * 32 + ln) * 4 + km * 2 + kh);

    const int mbase = m0 + ln;                      // A fragment row base

    v16i acc[2][2];
#pragma unroll
    for (int rt = 0; rt < 2; ++rt)
#pragma unroll
        for (int ct = 0; ct < 2; ++ct)
#pragma unroll
            for (int e = 0; e < 16; ++e) acc[rt][ct][e] = 0;

    // prologue: prime both buffers; wait stage(0) (stage(1) stays in flight)
    STAGE_B(0, 0);
    STAGE_B(1, 64);
    asm volatile("s_waitcnt vmcnt(4)" ::: "memory");

#pragma unroll
    for (int s = 0; s < NSTEP; ++s) {
        const int buf = s & 1;

        // 1. B fragments from LDS (stage(s) complete by induction)
        uint4 bf[2][2];
#pragma unroll
        for (int km = 0; km < 2; ++km)
#pragma unroll
            for (int ct = 0; ct < 2; ++ct) bf[km][ct] = sB[buf][offB[km][ct]];

        // 2. A fragments direct from global (coalesced, L1/L2-hot)
        uint4 af[2][2];
#pragma unroll
        for (int km = 0; km < 2; ++km)
#pragma unroll
            for (int rt = 0; rt < 2; ++rt)
                af[km][rt] = aT4[(size_t)(s * 4 + km * 2 + kh) * BATCH
                                 + mbase + rt * 32];

        // 3. our reads of buf done -> safe to restage it with k(s+2)
        asm volatile("s_waitcnt lgkmcnt(0)" ::: "memory");
        if (s + 2 < NSTEP) STAGE_B(buf, (s + 2) * 64);

        // 4. retire af(s) + stage(s+1); stage(s+2) (4 loads) stays in flight
        if (s + 2 < NSTEP)
            asm volatile("s_waitcnt vmcnt(4)" ::: "memory");
        else
            asm volatile("s_waitcnt vmcnt(0)" ::: "memory");

        // 5. MFMA cluster
#pragma unroll
        for (int km = 0; km < 2; ++km)
#pragma unroll
            for (int rt = 0; rt < 2; ++rt)
#pragma unroll
                for (int ct = 0; ct < 2; ++ct)
                    acc[rt][ct] = __builtin_amdgcn_mfma_i32_32x32x32_i8(
                        *(v4i*)&af[km][rt], *(v4i*)&bf[km][ct], acc[rt][ct], 0, 0, 0);
    }

    // ---- epilogue: packed argmin, exact tie-break (verified r6-r12) -------
    int sk[2];
#pragma unroll
    for (int ct = 0; ct < 2; ++ct) sk[ct] = sumk[n0 + ct * 32 + ln];

#pragma unroll
    for (int rt = 0; rt < 2; ++rt) {
#pragma unroll
        for (int r = 0; r < 16; ++r) {
            // verified C/D map: col = lane&31, row = (r&3)+8*(r>>2)+4*(lane>>5)
            const int qrow = m0 + rt * 32 + (r & 3) + 8 * (r >> 2) + 4 * kh;
            uint32_t bmin = 0xFFFFFFFFu;
#pragma unroll
            for (int ct = 0; ct < 2; ++ct) {
                uint32_t dist = (uint32_t)(sk[ct] - 2 * acc[rt][ct][r] + 2048);
                uint32_t col  = (uint32_t)(n0 + ct * 32 + ln);
                bmin = min(bmin, (dist << 16) | col);
            }
#pragma unroll
            for (int off = 1; off < 32; off <<= 1)   // reduce within 32 cols
                bmin = min(bmin, (uint32_t)__shfl_xor((int)bmin, off, 64));
            if (ln == 0) atomicMin(&best[qrow], bmin);
        }
    }
}

// ---- best[q] -> gather values row ------------------------------------------
__global__ void finalize_kernel(const uint32_t* __restrict__ best,
                                const float* __restrict__ values,
                                float* __restrict__ out) {
    const int qy  = blockIdx.x;
    const int idx = (int)(best[qy] & 0xFFFFu);
    const float4* v4 = reinterpret_cast<const float4*>(values) + (size_t)idx * 256;
    float4* o4 = reinterpret_cast<float4*>(out) + (size_t)qy * 256;
    o4[threadIdx.x] = v4[threadIdx.x];
}

// ===========================================================================
// Fallback (round-5 VALU scan, 401 us) if ws_size can't hold i8 keys
// ===========================================================================
#define KCHUNK 256
#define NSPLIT (CAPACITY / KCHUNK)

__device__ __forceinline__ uint32_t pack_word(const int4* __restrict__ p) {
    uint32_t word = 0;
#pragma unroll
    for (int j = 0; j < 8; ++j) {
        int4 v = p[j];
        word |= (uint32_t)(v.x & 1) << (4 * j + 0);
        word |= (uint32_t)(v.y & 1) << (4 * j + 1);
        word |= (uint32_t)(v.z & 1) << (4 * j + 2);
        word |= (uint32_t)(v.w & 1) << (4 * j + 3);
    }
    return word;
}

__global__ void pack_bits_kernel(const int* __restrict__ in,
                                 uint32_t* __restrict__ out, int nwords) {
    int w = blockIdx.x * blockDim.x + threadIdx.x;
    if (w >= nwords) return;
    out[w] = pack_word(reinterpret_cast<const int4*>(in) + (size_t)w * 8);
}

__launch_bounds__(256, 4)
__global__ void scan_kernel(const uint32_t* __restrict__ qpack,
                            const uint32_t* __restrict__ kpack,
                            uint32_t* __restrict__ best) {
    const int t      = threadIdx.x;
    const int lane   = t & 63;
    const int wid    = t >> 6;
    const int ksplit = blockIdx.x & (NSPLIT - 1);
    const int qgb    = blockIdx.x >> 8;
    const int query  = qgb * 256 + wid * 64 + lane;

    uint32_t q[32];
    const uint4* qp4 = reinterpret_cast<const uint4*>(qpack + (size_t)query * 32);
#pragma unroll
    for (int j = 0; j < 8; ++j) {
        uint4 v = qp4[j];
        q[4 * j + 0] = v.x; q[4 * j + 1] = v.y;
        q[4 * j + 2] = v.z; q[4 * j + 3] = v.w;
    }
    uint32_t bst = 0xFFFFFFFFu;
    const int k0 = ksplit * KCHUNK;
#pragma unroll 2
    for (int k = k0; k < k0 + KCHUNK; ++k) {
        const uint4* kw4 = reinterpret_cast<const uint4*>(kpack + (size_t)k * 32);
        uint32_t dist = 0;
#pragma unroll
        for (int j = 0; j < 8; ++j) {
            uint4 kv = kw4[j];
            dist += __popc(kv.x ^ q[4 * j + 0]);
            dist += __popc(kv.y ^ q[4 * j + 1]);
            dist += __popc(kv.z ^ q[4 * j + 2]);
            dist += __popc(kv.w ^ q[4 * j + 3]);
        }
        bst = min(bst, (dist << 16) | (uint32_t)k);
    }
    atomicMin(&best[query], bst);
}

// ===========================================================================
extern "C" void kernel_launch(void* const* d_in, const int* in_sizes, int n_in,
                              void* d_out, int out_size, void* d_ws, size_t ws_size,
                              hipStream_t stream) {
    const int*   query  = (const int*)d_in[0];   // [2048, 1024] int32 0/1
    const int*   keys   = (const int*)d_in[1];   // [65536, 1024] int32 0/1
    const float* values = (const float*)d_in[2]; // [65536, 1024] f32
    float*       out    = (float*)d_out;         // [2048, 1024] f32
    char* ws = (char*)d_ws;

    const size_t need = 2097152ULL + 67108864ULL + 262144ULL + 8192ULL;
    if (ws_size >= need) {
        uint32_t* qT  = (uint32_t*)ws;                           // 2 MB blocked-T
        unsigned char* ki8 = (unsigned char*)(ws + 2097152);     // 64 MB
        int* sumk = (int*)(ws + 2097152 + 67108864);             // 256 KB
        uint32_t* best = (uint32_t*)(ws + 2097152 + 67108864 + 262144);

        init_best_kernel<<<BATCH / 256, 256, 0, stream>>>(best);
        prep_qT_kernel<<<BATCH,    256, 0, stream>>>(query, qT);
        prep_i8_kernel<<<CAPACITY, 256, 0, stream>>>(keys, ki8, sumk);
        gemm_scan_kernel<<<32 * 1024, 64, 0, stream>>>(
            reinterpret_cast<const uint4*>(qT), ki8, sumk, best);
        finalize_kernel<<<BATCH, 256, 0, stream>>>(best, values, out);
    } else {
        uint32_t* qpack = (uint32_t*)ws;                         // 256 KB
        uint32_t* kpack = (uint32_t*)(ws + 262144);              // 8 MB
        uint32_t* best  = (uint32_t*)(ws + 262144 + 8388608);    // 8 KB

        init_best_kernel<<<BATCH / 256, 256, 0, stream>>>(best);
        pack_bits_kernel<<<BATCH * 32 / 256, 256, 0, stream>>>(query, qpack, BATCH * 32);
        pack_bits_kernel<<<CAPACITY * 32 / 256, 256, 0, stream>>>(keys, kpack, CAPACITY * 32);
        scan_kernel<<<8 * NSPLIT, 256, 0, stream>>>(qpack, kpack, best);
        finalize_kernel<<<BATCH, 256, 0, stream>>>(best, values, out);
    }
}

// Round 14
// 280.764 us; speedup vs baseline: 3.1522x; 3.1522x over previous
//
#include <hip/hip_runtime.h>
#include <stdint.h>

typedef int v4i  __attribute__((ext_vector_type(4)));
typedef int v16i __attribute__((ext_vector_type(16)));

#define CAPACITY  65536
#define BATCH     2048
#define KBITS     1024
#define NSTEP     16      // K-steps of 64 bytes

// ===========================================================================
// MFMA path: dist(q,k) = sumq + sumk - 2*dot(q,k). sumq constant per query
// row -> dropped; rank by packed ((sumk - 2*dot + 2048)<<16) | key_idx, exact
// (0 <= biased dist <= 3072 < 2^16), reproduces first-max argmax.
//
// Geometry: block 256(M) x 64(N), 4 waves = 4 M-rows (wave tile 64x64).
// A fragments per wave are UNIQUE (no cross-wave duplication); the 4 KB/step
// B tile is staged once via global_load_lds and shared by all 4 waves.
// af double-buffered across the barrier (issued top-of-step, used next step);
// exact in-order vmcnt counts keep stage(s+2) and af(s+1) in flight at every
// wait. Per-CU-step pipe demand (4 blocks/CU): MFMA ~1171 cyc, L1 ~1250,
// LDS ~625 -> balanced, unlike r12 (L1 1500) and r13 (HBM blowup).
// ===========================================================================

// ---- queries: bits -> i8, blocked-transposed qT[k/16][m][16] ----------------
__global__ void prep_qT_kernel(const int* __restrict__ in,
                               uint32_t* __restrict__ outT) {
    const int row = blockIdx.x, t = threadIdx.x;   // t covers bits 4t..4t+3
    int4 v = reinterpret_cast<const int4*>(in)[(size_t)row * 256 + t];
    uint32_t b = (uint32_t)(v.x & 1)        | ((uint32_t)(v.y & 1) << 8) |
                 ((uint32_t)(v.z & 1) << 16) | ((uint32_t)(v.w & 1) << 24);
    outT[(size_t)(t >> 2) * (BATCH * 4) + (size_t)row * 4 + (t & 3)] = b;
}

// ---- keys: bits -> i8 row-major, plus per-row bit count ---------------------
__global__ void prep_i8_kernel(const int* __restrict__ in,
                               unsigned char* __restrict__ out8,
                               int* __restrict__ sums) {
    const int row = blockIdx.x, t = threadIdx.x;
    int4 v = reinterpret_cast<const int4*>(in)[(size_t)row * 256 + t];
    uint32_t b = (uint32_t)(v.x & 1)        | ((uint32_t)(v.y & 1) << 8) |
                 ((uint32_t)(v.z & 1) << 16) | ((uint32_t)(v.w & 1) << 24);
    reinterpret_cast<uint32_t*>(out8)[(size_t)row * 256 + t] = b;
    int s = (v.x & 1) + (v.y & 1) + (v.z & 1) + (v.w & 1);
    for (int off = 32; off; off >>= 1) s += __shfl_xor(s, off, 64);
    __shared__ int ws4[4];
    if ((t & 63) == 0) ws4[t >> 6] = s;
    __syncthreads();
    if (t == 0) sums[row] = ws4[0] + ws4[1] + ws4[2] + ws4[3];
}

__global__ void init_best_kernel(uint32_t* __restrict__ best) {
    best[blockIdx.x * 256 + threadIdx.x] = 0xFFFFFFFFu;
}

// Involutive 16B-chunk swizzle within a [rows][64B] tile (idx = row*4+chunk):
// self-inverse, spreads consecutive rows across bank groups.
__device__ __forceinline__ int swz(int idx) { return idx ^ ((idx >> 3) & 7); }

// ---- GEMM + fused argmin ---------------------------------------------------
__launch_bounds__(256, 4)
__global__ void gemm_scan_kernel(const uint4* __restrict__ aT4,
                                 const unsigned char* __restrict__ ki8,
                                 const int* __restrict__ sumk,
                                 uint32_t* __restrict__ best) {
    __shared__ uint4 sB[3][256];   // 3 x (64 rows x 4 chunks) = 12 KB

    const int t    = threadIdx.x;
    const int lane = t & 63, wid = t >> 6;        // wid = wave M-row
    const int ln   = lane & 31, kh = lane >> 5;   // mfma lane, k-half

    // mtile-inner, XCD-pinned: xcd = b&7 owns 128 ntiles; 8 consecutive
    // blocks share one B-tile (L2-hot); A (2 MB qT) cycles through L2.
    const int b     = blockIdx.x;
    const int slot  = b >> 3;                      // [0,1024)
    const int ntile = (b & 7) * 128 + (slot >> 3); // [0,1024)
    const int mtile = slot & 7;                    // [0,8)
    const int m0 = mtile * 256, n0 = ntile * 64;

    // B staging source, pre-swizzled (swz involution; LDS dest linear):
    // LDS slot t holds global 16B-chunk swz(t) of the 64x64B tile.
    const int sidx = swz(t);
    const unsigned char* bSrc =
        ki8 + (size_t)(n0 + (sidx >> 2)) * KBITS + (sidx & 3) * 16;
    auto STAGE_B = [&](int buf, int kc) {          // 1 x global_load_lds(16B)
        __builtin_amdgcn_global_load_lds(
            (const __attribute__((address_space(1))) void*)(bSrc + kc),
            (__attribute__((address_space(3))) void*)&sB[buf][wid * 64],
            16, 0, 0);
    };

    // B fragment LDS offsets (K-invariant), shared tile for all waves
    int offB[2][2];
#pragma unroll
    for (int km = 0; km < 2; ++km)
#pragma unroll
        for (int ct = 0; ct < 2; ++ct)
            offB[km][ct] = swz((ct * 32 + ln) * 4 + km * 2 + kh);

    const int mbase = m0 + wid * 64 + ln;          // unique per wave

    v16i acc[2][2];
#pragma unroll
    for (int rt = 0; rt < 2; ++rt)
#pragma unroll
        for (int ct = 0; ct < 2; ++ct)
#pragma unroll
            for (int e = 0; e < 16; ++e) acc[rt][ct][e] = 0;

    uint4 afbuf[2][2][2];                          // [parity][km][rt]
    auto LOAD_AF = [&](int par, int s) {
#pragma unroll
        for (int km = 0; km < 2; ++km)
#pragma unroll
            for (int rt = 0; rt < 2; ++rt)
                afbuf[par][km][rt] = aT4[(size_t)(s * 4 + km * 2 + kh) * BATCH
                                         + mbase + rt * 32];
    };

    // prologue: queue = stage(0)[1], stage(1)[1], af(0)[4].
    // vmcnt(5) retires stage(0); stage(1)+af(0) stay in flight.
    STAGE_B(0, 0);
    STAGE_B(1, 64);
    LOAD_AF(0, 0);
    asm volatile("s_waitcnt vmcnt(5)" ::: "memory");
    __builtin_amdgcn_s_barrier();

#pragma unroll
    for (int s = 0; s < NSTEP; ++s) {
        const int par = s & 1, buf = s % 3;

        if (s + 1 < NSTEP) LOAD_AF(par ^ 1, s + 1);       // 4 vm, 1-step slack
        if (s + 2 < NSTEP) STAGE_B((s + 2) % 3, (s + 2) * 64); // 1 vm, 2-step

        // B fragments: km=0 pair then km=1 pair (counted lgkm overlap)
        uint4 bf0[2], bf1[2];
#pragma unroll
        for (int ct = 0; ct < 2; ++ct) bf0[ct] = sB[buf][offB[0][ct]];
#pragma unroll
        for (int ct = 0; ct < 2; ++ct) bf1[ct] = sB[buf][offB[1][ct]];

        // retire af(s) (+ all older, incl. stage(s)); bf0 ready.
        // younger left in flight: stage(s+1), af(s+1), stage(s+2).
        if (s == 0)
            asm volatile("s_waitcnt vmcnt(5) lgkmcnt(2)" ::: "memory");
        else if (s <= 13)
            asm volatile("s_waitcnt vmcnt(6) lgkmcnt(2)" ::: "memory");
        else if (s == 14)
            asm volatile("s_waitcnt vmcnt(5) lgkmcnt(2)" ::: "memory");
        else
            asm volatile("s_waitcnt vmcnt(0) lgkmcnt(2)" ::: "memory");
        __builtin_amdgcn_sched_barrier(0);

        __builtin_amdgcn_s_setprio(1);
#pragma unroll
        for (int rt = 0; rt < 2; ++rt)
#pragma unroll
            for (int ct = 0; ct < 2; ++ct)
                acc[rt][ct] = __builtin_amdgcn_mfma_i32_32x32x32_i8(
                    *(v4i*)&afbuf[par][0][rt], *(v4i*)&bf0[ct], acc[rt][ct], 0, 0, 0);
        __builtin_amdgcn_s_setprio(0);

        asm volatile("s_waitcnt lgkmcnt(0)" ::: "memory");   // bf1 ready
        __builtin_amdgcn_sched_barrier(0);

        __builtin_amdgcn_s_setprio(1);
#pragma unroll
        for (int rt = 0; rt < 2; ++rt)
#pragma unroll
            for (int ct = 0; ct < 2; ++ct)
                acc[rt][ct] = __builtin_amdgcn_mfma_i32_32x32x32_i8(
                    *(v4i*)&afbuf[par][1][rt], *(v4i*)&bf1[ct], acc[rt][ct], 0, 0, 0);
        __builtin_amdgcn_s_setprio(0);

        if (s < NSTEP - 1) {
            // retire own stage(s+1) share before barrier; leave af(s+1)
            // (+stage(s+2)) in flight. Our ds_reads already drained (lgkm 0).
            if (s <= 13)
                asm volatile("s_waitcnt vmcnt(5)" ::: "memory");
            else
                asm volatile("s_waitcnt vmcnt(4)" ::: "memory");
            __builtin_amdgcn_s_barrier();
        }
    }

    // ---- epilogue: packed argmin, exact tie-break (verified r6-r12) -------
    int sk[2];
#pragma unroll
    for (int ct = 0; ct < 2; ++ct) sk[ct] = sumk[n0 + ct * 32 + ln];

#pragma unroll
    for (int rt = 0; rt < 2; ++rt) {
#pragma unroll
        for (int r = 0; r < 16; ++r) {
            // verified C/D map: col = lane&31, row = (r&3)+8*(r>>2)+4*(lane>>5)
            const int qrow = m0 + wid * 64 + rt * 32 + (r & 3) + 8 * (r >> 2) + 4 * kh;
            uint32_t bmin = 0xFFFFFFFFu;
#pragma unroll
            for (int ct = 0; ct < 2; ++ct) {
                uint32_t dist = (uint32_t)(sk[ct] - 2 * acc[rt][ct][r] + 2048);
                uint32_t col  = (uint32_t)(n0 + ct * 32 + ln);
                bmin = min(bmin, (dist << 16) | col);
            }
#pragma unroll
            for (int off = 1; off < 32; off <<= 1)   // reduce within 32 cols
                bmin = min(bmin, (uint32_t)__shfl_xor((int)bmin, off, 64));
            if (ln == 0) atomicMin(&best[qrow], bmin);
        }
    }
}

// ---- best[q] -> gather values row ------------------------------------------
__global__ void finalize_kernel(const uint32_t* __restrict__ best,
                                const float* __restrict__ values,
                                float* __restrict__ out) {
    const int qy  = blockIdx.x;
    const int idx = (int)(best[qy] & 0xFFFFu);
    const float4* v4 = reinterpret_cast<const float4*>(values) + (size_t)idx * 256;
    float4* o4 = reinterpret_cast<float4*>(out) + (size_t)qy * 256;
    o4[threadIdx.x] = v4[threadIdx.x];
}

// ===========================================================================
// Fallback (round-5 VALU scan, 401 us) if ws_size can't hold i8 keys
// ===========================================================================
#define KCHUNK 256
#define NSPLIT (CAPACITY / KCHUNK)

__device__ __forceinline__ uint32_t pack_word(const int4* __restrict__ p) {
    uint32_t word = 0;
#pragma unroll
    for (int j = 0; j < 8; ++j) {
        int4 v = p[j];
        word |= (uint32_t)(v.x & 1) << (4 * j + 0);
        word |= (uint32_t)(v.y & 1) << (4 * j + 1);
        word |= (uint32_t)(v.z & 1) << (4 * j + 2);
        word |= (uint32_t)(v.w & 1) << (4 * j + 3);
    }
    return word;
}

__global__ void pack_bits_kernel(const int* __restrict__ in,
                                 uint32_t* __restrict__ out, int nwords) {
    int w = blockIdx.x * blockDim.x + threadIdx.x;
    if (w >= nwords) return;
    out[w] = pack_word(reinterpret_cast<const int4*>(in) + (size_t)w * 8);
}

__launch_bounds__(256, 4)
__global__ void scan_kernel(const uint32_t* __restrict__ qpack,
                            const uint32_t* __restrict__ kpack,
                            uint32_t* __restrict__ best) {
    const int t      = threadIdx.x;
    const int lane   = t & 63;
    const int wid    = t >> 6;
    const int ksplit = blockIdx.x & (NSPLIT - 1);
    const int qgb    = blockIdx.x >> 8;
    const int query  = qgb * 256 + wid * 64 + lane;

    uint32_t q[32];
    const uint4* qp4 = reinterpret_cast<const uint4*>(qpack + (size_t)query * 32);
#pragma unroll
    for (int j = 0; j < 8; ++j) {
        uint4 v = qp4[j];
        q[4 * j + 0] = v.x; q[4 * j + 1] = v.y;
        q[4 * j + 2] = v.z; q[4 * j + 3] = v.w;
    }
    uint32_t bst = 0xFFFFFFFFu;
    const int k0 = ksplit * KCHUNK;
#pragma unroll 2
    for (int k = k0; k < k0 + KCHUNK; ++k) {
        const uint4* kw4 = reinterpret_cast<const uint4*>(kpack + (size_t)k * 32);
        uint32_t dist = 0;
#pragma unroll
        for (int j = 0; j < 8; ++j) {
            uint4 kv = kw4[j];
            dist += __popc(kv.x ^ q[4 * j + 0]);
            dist += __popc(kv.y ^ q[4 * j + 1]);
            dist += __popc(kv.z ^ q[4 * j + 2]);
            dist += __popc(kv.w ^ q[4 * j + 3]);
        }
        bst = min(bst, (dist << 16) | (uint32_t)k);
    }
    atomicMin(&best[query], bst);
}

// ===========================================================================
extern "C" void kernel_launch(void* const* d_in, const int* in_sizes, int n_in,
                              void* d_out, int out_size, void* d_ws, size_t ws_size,
                              hipStream_t stream) {
    const int*   query  = (const int*)d_in[0];   // [2048, 1024] int32 0/1
    const int*   keys   = (const int*)d_in[1];   // [65536, 1024] int32 0/1
    const float* values = (const float*)d_in[2]; // [65536, 1024] f32
    float*       out    = (float*)d_out;         // [2048, 1024] f32
    char* ws = (char*)d_ws;

    const size_t need = 2097152ULL + 67108864ULL + 262144ULL + 8192ULL;
    if (ws_size >= need) {
        uint32_t* qT  = (uint32_t*)ws;                           // 2 MB blocked-T
        unsigned char* ki8 = (unsigned char*)(ws + 2097152);     // 64 MB
        int* sumk = (int*)(ws + 2097152 + 67108864);             // 256 KB
        uint32_t* best = (uint32_t*)(ws + 2097152 + 67108864 + 262144);

        init_best_kernel<<<BATCH / 256, 256, 0, stream>>>(best);
        prep_qT_kernel<<<BATCH,    256, 0, stream>>>(query, qT);
        prep_i8_kernel<<<CAPACITY, 256, 0, stream>>>(keys, ki8, sumk);
        gemm_scan_kernel<<<8192, 256, 0, stream>>>(
            reinterpret_cast<const uint4*>(qT), ki8, sumk, best);
        finalize_kernel<<<BATCH, 256, 0, stream>>>(best, values, out);
    } else {
        uint32_t* qpack = (uint32_t*)ws;                         // 256 KB
        uint32_t* kpack = (uint32_t*)(ws + 262144);              // 8 MB
        uint32_t* best  = (uint32_t*)(ws + 262144 + 8388608);    // 8 KB

        init_best_kernel<<<BATCH / 256, 256, 0, stream>>>(best);
        pack_bits_kernel<<<BATCH * 32 / 256, 256, 0, stream>>>(query, qpack, BATCH * 32);
        pack_bits_kernel<<<CAPACITY * 32 / 256, 256, 0, stream>>>(keys, kpack, CAPACITY * 32);
        scan_kernel<<<8 * NSPLIT, 256, 0, stream>>>(qpack, kpack, best);
        finalize_kernel<<<BATCH, 256, 0, stream>>>(best, values, out);
    }
}